// Round 3
// baseline (578.939 us; speedup 1.0000x reference)
//
#include <hip/hip_runtime.h>
#include <cstdint>
#include <cstddef>
#include <math.h>

#define T_TOK 32768
#define DIM   1024
#define DFF   256
#define NE    8
#define NB    16                 // (expert, slot) bins
#define ROWS  (T_TOK * 2)        // 65536 token-expert rows
#define MAXROWS 66560            // ROWS + 16*63 pad, rounded to x64
#define MAXTILES (MAXROWS / 64)  // 1040 (64-row tiles)

typedef unsigned short u16;
typedef __attribute__((ext_vector_type(8))) short v8s;   // 8 bf16 (4 VGPR)
typedef __attribute__((ext_vector_type(4))) float v4f;   // MFMA acc

__device__ __forceinline__ u16 f2bf(float f) {
  union { float f; unsigned u; } v; v.f = f;
  return (u16)((v.u + 0x7FFFu + ((v.u >> 16) & 1u)) >> 16);  // RNE
}
__device__ __forceinline__ float bf2f(u16 b) {
  union { unsigned u; float f; } v; v.u = ((unsigned)b) << 16; return v.f;
}

// async global->LDS, 16B per lane; LDS dest = wave-uniform base + lane*16
__device__ __forceinline__ void gload16(const u16* g, u16* l) {
  __builtin_amdgcn_global_load_lds(
      (const __attribute__((address_space(1))) void*)g,
      (__attribute__((address_space(3))) void*)l, 16, 0, 0);
}

// ---------------- ws layout (bytes) ----------------
#define WS_W13  ((size_t)0)              // 8*512*1024*2   = 8388608
#define WS_W2T  ((size_t)8388608)        // 8*1024*256*2   = 4194304
#define WS_H    ((size_t)12582912)       // 66560*256*2    = 34078720
#define WS_Y    ((size_t)46661632)       // 66560*1024*2   = 136314880
#define WS_RTOK ((size_t)182976512)      // 66560*4        = 266240
#define WS_POS  ((size_t)183242752)      // 65536*4        = 262144
#define WS_CNT  ((size_t)183504896)      // 16*4 pad 64
#define WS_CUR  ((size_t)183504960)      // 16*4 pad 64
#define WS_OFF  ((size_t)183505024)      // 17*4 pad 128
#define WS_SEL  ((size_t)183505152)      // 65536*4        = 262144
#define WS_WTS  ((size_t)183767296)      // 65536*4  -> total 184029440
// xb (bf16 x, 32768*1024*2 = 67108864 B) ALIASES the Y region: written by
// k_router, consumed by k_gemm1, dead before k_gemm2 overwrites Y.
#define WS_XB   WS_Y

// ============ weight packing: w1/w3 -> W13p[e][n=512][k=1024] bf16 ============
__global__ __launch_bounds__(256) void k_pack13(const float* __restrict__ w1,
                                                const float* __restrict__ w3,
                                                u16* __restrict__ W13p) {
  __shared__ float s1[32][33];
  __shared__ float s3[32][33];
  int e = blockIdx.z, k0 = blockIdx.x * 32, j0w = blockIdx.y;
  int tx = threadIdx.x, ty = threadIdx.y;
  size_t wbase = (size_t)e * DIM * DFF;
#pragma unroll
  for (int r = 0; r < 4; ++r) {
    int kl = ty + 8 * r;
    size_t src = wbase + (size_t)(k0 + kl) * DFF + j0w * 32 + tx;
    s1[kl][tx] = w1[src];
    s3[kl][tx] = w3[src];
  }
  __syncthreads();
  size_t obase = (size_t)e * 512 * 1024;
#pragma unroll
  for (int r = 0; r < 4; ++r) {
    int jl = ty + 8 * r;
    int n1 = 64 * j0w + jl;
    W13p[obase + (size_t)n1 * 1024 + k0 + tx]        = f2bf(s1[tx][jl]);
    W13p[obase + (size_t)(n1 + 32) * 1024 + k0 + tx] = f2bf(s3[tx][jl]);
  }
}

// ============ w2 [e][k=256][n=1024] -> W2t[e][n=1024][k=256] bf16 ============
__global__ __launch_bounds__(256) void k_pack2(const float* __restrict__ w2,
                                               u16* __restrict__ W2t) {
  __shared__ float s[32][33];
  int e = blockIdx.z, k0 = blockIdx.x * 32, n0 = blockIdx.y * 32;
  int tx = threadIdx.x, ty = threadIdx.y;
#pragma unroll
  for (int r = 0; r < 4; ++r) {
    int kl = ty + 8 * r;
    s[kl][tx] = w2[(size_t)e * DFF * DIM + (size_t)(k0 + kl) * DIM + n0 + tx];
  }
  __syncthreads();
#pragma unroll
  for (int r = 0; r < 4; ++r) {
    int nl = ty + 8 * r;
    W2t[(size_t)e * DIM * DFF + (size_t)(n0 + nl) * DFF + k0 + tx] = f2bf(s[tx][nl]);
  }
}

// ============ router: np-order fp32 logits, LDS-staged; also emits xb bf16 ====
__global__ __launch_bounds__(256) void k_router(const float* __restrict__ x,
                                                const float* __restrict__ rw,
                                                int* __restrict__ sel,
                                                float* __restrict__ wts,
                                                int* __restrict__ cnt,
                                                u16* __restrict__ xb) {
  __shared__ __align__(16) float s_rw[NE][1028];
  __shared__ __align__(16) float s_x[32][132];
  __shared__ float s_lg[256];
  __shared__ int s_cnt[NB];
  int tid = threadIdx.x;
  if (tid < NB) s_cnt[tid] = 0;
  {
    const float4* rw4 = (const float4*)rw;
#pragma unroll
    for (int r = 0; r < 8; ++r)
      *(float4*)(&s_rw[r][tid * 4]) = rw4[r * 256 + tid];
  }
  int tl = tid >> 3, e = tid & 7;
  float acc = 0.0f;
  const float4* x4 = (const float4*)x;
  for (int c = 0; c < 8; ++c) {          // 8 chunks of 128 k
    __syncthreads();
#pragma unroll
    for (int j = 0; j < 4; ++j) {
      int slot = j * 256 + tid;
      int t = slot >> 5, kk = (slot & 31) * 4;
      *(float4*)(&s_x[t][kk]) = x4[((size_t)blockIdx.x * 32 + t) * 256 + c * 32 + (slot & 31)];
    }
    __syncthreads();
    const float* xp = &s_x[tl][0];
    const float* wp = &s_rw[e][c * 128];
#pragma unroll 16
    for (int k = 0; k < 128; ++k) acc = fmaf(xp[k], wp[k], acc);  // strict sequential
    // emit bf16 x for this chunk (same RNE f2bf -> bit-identical GEMM1)
    {
      int t2 = tid >> 3, k2 = (tid & 7) * 16;
      const float* sp = &s_x[t2][k2];
      u16 tb[16];
#pragma unroll
      for (int k = 0; k < 16; ++k) tb[k] = f2bf(sp[k]);
      u16* xo = xb + ((size_t)(blockIdx.x * 32 + t2)) * 1024 + c * 128 + k2;
      *(uint4*)(xo)     = *(const uint4*)(&tb[0]);
      *(uint4*)(xo + 8) = *(const uint4*)(&tb[8]);
    }
  }
  s_lg[tid] = acc;
  __syncthreads();
  if ((tid & 7) == 0) {
    int t = blockIdx.x * 32 + tl;
    const float* lg = s_lg + tid;
    int b0 = 0; float v0 = lg[0];
#pragma unroll
    for (int ee = 1; ee < NE; ++ee) if (lg[ee] > v0) { v0 = lg[ee]; b0 = ee; }
    int b1 = -1; float v1 = -1e30f;
#pragma unroll
    for (int ee = 0; ee < NE; ++ee) if (ee != b0 && lg[ee] > v1) { v1 = lg[ee]; b1 = ee; }
    float w0 = 1.0f / (1.0f + expf(v1 - v0));  // v1<=v0, safe
    sel[2 * t] = b0; sel[2 * t + 1] = b1;
    wts[2 * t] = w0; wts[2 * t + 1] = 1.0f - w0;
    atomicAdd(&s_cnt[2 * b0], 1);       // bin = expert*2 + slot
    atomicAdd(&s_cnt[2 * b1 + 1], 1);
  }
  __syncthreads();
  if (tid < NB && s_cnt[tid]) atomicAdd(&cnt[tid], s_cnt[tid]);
}

// ============ scan: padded (x64) exclusive offsets over 16 bins ============
__global__ void k_scan(const int* __restrict__ cnt, int* __restrict__ offs) {
  if (threadIdx.x == 0 && blockIdx.x == 0) {
    int o = 0;
#pragma unroll
    for (int b = 0; b < NB; ++b) { offs[b] = o; o += (cnt[b] + 63) & ~63; }
    offs[NB] = o;
  }
}

// ============ scatter: build (expert,slot)-sorted row lists + pos map ============
__global__ __launch_bounds__(256) void k_scatter(const int* __restrict__ sel,
                                                 const int* __restrict__ offs,
                                                 int* __restrict__ cursor,
                                                 int* __restrict__ rtok,
                                                 int* __restrict__ pos) {
  __shared__ int s_cnt[NB], s_base[NB];
  int tid = threadIdx.x;
  if (tid < NB) s_cnt[tid] = 0;
  __syncthreads();
  int g = blockIdx.x * 256 + tid;          // token*2 + slot
  int b = sel[g] * 2 + (g & 1);
  int lpos = atomicAdd(&s_cnt[b], 1);
  __syncthreads();
  if (tid < NB) s_base[tid] = s_cnt[tid] ? atomicAdd(&cursor[tid], s_cnt[tid]) : 0;
  __syncthreads();
  int row = offs[b] + s_base[b] + lpos;
  rtok[row] = g >> 1;
  pos[g] = row;
}

// =============================================================================
// GEMM1 + SwiGLU, m97 geometry: 128x128 tile, 4 waves, 64x64/wave, BK=32.
// 64-row tile indexing with PAIRING: even tile whose odd partner is in the
// same bin does 128 rows; partner exits. LDS dbuf 32KB -> 4 blocks/CU.
// =============================================================================
__global__ __launch_bounds__(256, 4) void k_gemm1(const u16* __restrict__ xb,
                                                  const u16* __restrict__ W13p,
                                                  const int* __restrict__ rtok,
                                                  const int* __restrict__ offs,
                                                  u16* __restrict__ h) {
  __shared__ __align__(16) u16 A_s[2][128][32];
  __shared__ __align__(16) u16 B_s[2][128][32];
  // chunked XCD swizzle (1040 % 8 == 0, chunks of 130 preserve pair parity)
  int bx = (int)((blockIdx.x & 7) * (MAXTILES / 8) + (blockIdx.x >> 3));
  int row0 = bx * 64;
  int totR = offs[NB];
  if (row0 >= totR) return;
  int b2 = 0;
  while (row0 >= offs[b2 + 1]) ++b2;
  int e = b2 >> 1;
  bool paired = (bx & 1) ? (row0 - 64 >= offs[b2]) : (row0 + 64 < offs[b2 + 1]);
  if (paired && (bx & 1)) return;          // odd partner handled by even tile
  int M = paired ? 128 : 64;
  int nb = blockIdx.y;                     // 128-col tile of W13p
  int tid = threadIdx.x;
  int wv = tid >> 6, lane = tid & 63;
  int wr = wv >> 1, wc = wv & 1;
  int lr = lane & 15, q = lane >> 4;
  int qa = q ^ ((lr >> 1) & 3);            // swizzled read chunk
  int srow = lane >> 2;                    // 0..15 within staged group
  int schk = (lane & 3) ^ ((lane >> 3) & 3);  // pre-swizzled source chunk
  // staging sources: wave wv stages A rows [32wv,32wv+32), B rows likewise
  const u16* srcA[2];
  const u16* srcB[2];
#pragma unroll
  for (int i = 0; i < 2; ++i) {
    int r = row0 + 32 * wv + 16 * i + srow;
    if (r > MAXROWS - 1) r = MAXROWS - 1;
    int tk = rtok[r];
    if (tk < 0 || tk >= T_TOK) tk = 0;     // pad/garbage row -> token 0
    srcA[i] = xb + (size_t)tk * 1024 + schk * 8;
    int n = nb * 128 + 32 * wv + 16 * i + srow;
    srcB[i] = W13p + (size_t)e * 512 * 1024 + (size_t)n * 1024 + schk * 8;
  }
  v4f acc[4][4] = {};

#define G1_STAGE(buf, k0) do {                                              \
    gload16(srcA[0] + (k0), &A_s[buf][32 * wv][0]);                         \
    gload16(srcA[1] + (k0), &A_s[buf][32 * wv + 16][0]);                    \
    gload16(srcB[0] + (k0), &B_s[buf][32 * wv][0]);                         \
    gload16(srcB[1] + (k0), &B_s[buf][32 * wv + 16][0]);                    \
  } while (0)

#define G1_COMP(buf) do {                                                   \
    v8s a_[4], b_[4];                                                       \
    _Pragma("unroll")                                                       \
    for (int mt_ = 0; mt_ < 4; ++mt_)                                       \
      a_[mt_] = *(const v8s*)(&A_s[buf][64 * wr + 16 * mt_ + lr][qa * 8]);  \
    _Pragma("unroll")                                                       \
    for (int nt_ = 0; nt_ < 4; ++nt_)                                       \
      b_[nt_] = *(const v8s*)(&B_s[buf][64 * wc + 16 * nt_ + lr][qa * 8]);  \
    _Pragma("unroll")                                                       \
    for (int mt_ = 0; mt_ < 4; ++mt_)                                       \
      _Pragma("unroll")                                                     \
      for (int nt_ = 0; nt_ < 4; ++nt_)                                     \
        acc[mt_][nt_] = __builtin_amdgcn_mfma_f32_16x16x32_bf16(            \
            a_[mt_], b_[nt_], acc[mt_][nt_], 0, 0, 0);                      \
  } while (0)

  G1_STAGE(0, 0);
  asm volatile("s_waitcnt vmcnt(0)" ::: "memory");
  __builtin_amdgcn_s_barrier();
  __builtin_amdgcn_sched_barrier(0);
#pragma unroll 2
  for (int t = 0; t < 31; ++t) {
    int cur = t & 1;
    G1_STAGE(cur ^ 1, (t + 1) * 32);       // next tile in flight during compute
    G1_COMP(cur);
    asm volatile("s_waitcnt vmcnt(0)" ::: "memory");
    __builtin_amdgcn_s_barrier();
    __builtin_amdgcn_sched_barrier(0);
  }
  G1_COMP(1);                              // t=31, buf 1, no prefetch

  // epilogue: n-block (2nb+wc): x1 = acc[][0..1], x3 = acc[][2..3]
  if (M == 128 || wr == 0) {
    int cb = 32 * (2 * nb + wc);
#pragma unroll
    for (int mt = 0; mt < 4; ++mt)
#pragma unroll
      for (int nt = 0; nt < 2; ++nt)
#pragma unroll
        for (int r = 0; r < 4; ++r) {
          float x1 = bf2f(f2bf(acc[mt][nt][r]));      // match ref bf16 rounding
          float x3 = bf2f(f2bf(acc[mt][nt + 2][r]));
          float hv = x1 * x3 / (1.0f + __expf(-x1));  // silu(x1)*x3
          int row = row0 + 64 * wr + 16 * mt + q * 4 + r;
          h[(size_t)row * DFF + cb + 16 * nt + lr] = f2bf(hv);
        }
  }
#undef G1_STAGE
#undef G1_COMP
}

// =============================================================================
// GEMM2: same geometry. 128x128 tile, K=256 (8 steps). LDS-transpose epilogue
// (per 16-row slab, wave-pair regions) for 16B coalesced y stores.
// =============================================================================
__global__ __launch_bounds__(256, 4) void k_gemm2(const u16* __restrict__ h,
                                                  const u16* __restrict__ W2t,
                                                  const int* __restrict__ offs,
                                                  u16* __restrict__ y) {
  __shared__ __align__(16) u16 A_s[2][128][32];
  __shared__ __align__(16) u16 B_s[2][128][32];
  int bx = (int)((blockIdx.x & 7) * (MAXTILES / 8) + (blockIdx.x >> 3));
  int row0 = bx * 64;
  int totR = offs[NB];
  if (row0 >= totR) return;
  int b2 = 0;
  while (row0 >= offs[b2 + 1]) ++b2;
  int e = b2 >> 1;
  bool paired = (bx & 1) ? (row0 - 64 >= offs[b2]) : (row0 + 64 < offs[b2 + 1]);
  if (paired && (bx & 1)) return;
  int M = paired ? 128 : 64;
  int nb = blockIdx.y;                     // 128-col tile of y
  int tid = threadIdx.x;
  int wv = tid >> 6, lane = tid & 63;
  int wr = wv >> 1, wc = wv & 1;
  int lr = lane & 15, q = lane >> 4;
  int qa = q ^ ((lr >> 1) & 3);
  int srow = lane >> 2;
  int schk = (lane & 3) ^ ((lane >> 3) & 3);
  const u16* srcA[2];
  const u16* srcB[2];
#pragma unroll
  for (int i = 0; i < 2; ++i) {
    int r = row0 + 32 * wv + 16 * i + srow;    // h rows; OOB stays inside ws
    srcA[i] = h + (size_t)r * DFF + schk * 8;
    int n = nb * 128 + 32 * wv + 16 * i + srow;
    srcB[i] = W2t + (size_t)e * DIM * DFF + (size_t)n * DFF + schk * 8;
  }
  v4f acc[4][4] = {};

#define G2_STAGE(buf, k0) do {                                              \
    gload16(srcA[0] + (k0), &A_s[buf][32 * wv][0]);                         \
    gload16(srcA[1] + (k0), &A_s[buf][32 * wv + 16][0]);                    \
    gload16(srcB[0] + (k0), &B_s[buf][32 * wv][0]);                         \
    gload16(srcB[1] + (k0), &B_s[buf][32 * wv + 16][0]);                    \
  } while (0)

#define G2_COMP(buf) do {                                                   \
    v8s a_[4], b_[4];                                                       \
    _Pragma("unroll")                                                       \
    for (int mt_ = 0; mt_ < 4; ++mt_)                                       \
      a_[mt_] = *(const v8s*)(&A_s[buf][64 * wr + 16 * mt_ + lr][qa * 8]);  \
    _Pragma("unroll")                                                       \
    for (int nt_ = 0; nt_ < 4; ++nt_)                                       \
      b_[nt_] = *(const v8s*)(&B_s[buf][64 * wc + 16 * nt_ + lr][qa * 8]);  \
    _Pragma("unroll")                                                       \
    for (int mt_ = 0; mt_ < 4; ++mt_)                                       \
      _Pragma("unroll")                                                     \
      for (int nt_ = 0; nt_ < 4; ++nt_)                                     \
        acc[mt_][nt_] = __builtin_amdgcn_mfma_f32_16x16x32_bf16(            \
            a_[mt_], b_[nt_], acc[mt_][nt_], 0, 0, 0);                      \
  } while (0)

  G2_STAGE(0, 0);
  asm volatile("s_waitcnt vmcnt(0)" ::: "memory");
  __builtin_amdgcn_s_barrier();
  __builtin_amdgcn_sched_barrier(0);
#pragma unroll 2
  for (int t = 0; t < 7; ++t) {
    int cur = t & 1;
    G2_STAGE(cur ^ 1, (t + 1) * 32);
    G2_COMP(cur);
    asm volatile("s_waitcnt vmcnt(0)" ::: "memory");
    __builtin_amdgcn_s_barrier();
    __builtin_amdgcn_sched_barrier(0);
  }
  G2_COMP(1);                              // t=7, buf 1
  __syncthreads();                         // done with A_s before Ts reuse

  // epilogue: slab j (16 rows) per wr-half; Ts[wr][16][136] in A_s space
  u16* Ts = &A_s[0][0][0];
#pragma unroll
  for (int j = 0; j < 4; ++j) {
    if (M == 128 || wr == 0) {
#pragma unroll
      for (int nt = 0; nt < 4; ++nt)
#pragma unroll
        for (int r = 0; r < 4; ++r)
          Ts[wr * 16 * 136 + (q * 4 + r) * 136 + 64 * wc + 16 * nt + lr] =
              f2bf(acc[j][nt][r]);
    }
    __syncthreads();
    if (M == 128 || wr == 0) {
#pragma unroll
      for (int i = 0; i < 2; ++i) {
        int u = wc * 64 + lane + 128 * i;  // 0..255 per wr-half
        int rr = u >> 4, cc = u & 15;
        uint4 v = *(const uint4*)(Ts + wr * 16 * 136 + rr * 136 + cc * 8);
        int grow = row0 + 64 * wr + 16 * j + rr;
        *(uint4*)(y + (size_t)grow * 1024 + nb * 128 + cc * 8) = v;
      }
    }
    __syncthreads();
  }
#undef G2_STAGE
#undef G2_COMP
}

// ============ combine: out[t] = w0*fp32(y[pos0]) + w1*fp32(y[pos1]) ============
__global__ __launch_bounds__(256) void k_combine(const u16* __restrict__ y,
                                                 const int* __restrict__ pos,
                                                 const float* __restrict__ wts,
                                                 float* __restrict__ out) {
  int tid = threadIdx.x, wv = tid >> 6, lane = tid & 63;
  int t = blockIdx.x * 4 + wv;
  int r0 = pos[2 * t], r1 = pos[2 * t + 1];
  float w0 = wts[2 * t], w1 = wts[2 * t + 1];
  const uint4* y0 = (const uint4*)(y + (size_t)r0 * 1024);
  const uint4* y1 = (const uint4*)(y + (size_t)r1 * 1024);
  float* o = out + (size_t)t * 1024;
#pragma unroll
  for (int i = 0; i < 2; ++i) {
    int j = lane + 64 * i;                   // 128 uint4 per row
    uint4 a = y0[j], b = y1[j];
    const u16* pa = (const u16*)&a;
    const u16* pb = (const u16*)&b;
    float f[8];
#pragma unroll
    for (int k = 0; k < 8; ++k) f[k] = bf2f(pa[k]) * w0 + bf2f(pb[k]) * w1;
    *(float4*)(o + j * 8)     = *(float4*)&f[0];
    *(float4*)(o + j * 8 + 4) = *(float4*)&f[4];
  }
}

extern "C" void kernel_launch(void* const* d_in, const int* in_sizes, int n_in,
                              void* d_out, int out_size, void* d_ws, size_t ws_size,
                              hipStream_t stream) {
  (void)in_sizes; (void)n_in; (void)ws_size; (void)out_size;
  const float* x  = (const float*)d_in[0];
  const float* rw = (const float*)d_in[1];
  const float* w1 = (const float*)d_in[2];
  const float* w2 = (const float*)d_in[3];
  const float* w3 = (const float*)d_in[4];
  float* out = (float*)d_out;
  char* ws = (char*)d_ws;
  u16*   W13p = (u16*)(ws + WS_W13);
  u16*   W2t  = (u16*)(ws + WS_W2T);
  u16*   hbuf = (u16*)(ws + WS_H);
  u16*   ybuf = (u16*)(ws + WS_Y);
  u16*   xbuf = (u16*)(ws + WS_XB);   // aliases ybuf: dead before k_gemm2 writes
  int*   rtok = (int*)(ws + WS_RTOK);
  int*   pos  = (int*)(ws + WS_POS);
  int*   cnt  = (int*)(ws + WS_CNT);
  int*   cur  = (int*)(ws + WS_CUR);
  int*   offs = (int*)(ws + WS_OFF);
  int*   sel  = (int*)(ws + WS_SEL);
  float* wts  = (float*)(ws + WS_WTS);

  hipMemsetAsync(ws + WS_RTOK, 0xFF, (size_t)MAXROWS * 4, stream);  // rtok = -1 (pad marker)
  hipMemsetAsync(ws + WS_CNT, 0, 128, stream);                      // cnt, cur

  k_pack13<<<dim3(32, 8, 8), dim3(32, 8), 0, stream>>>(w1, w3, W13p);
  k_pack2 <<<dim3(8, 32, 8), dim3(32, 8), 0, stream>>>(w2, W2t);
  k_router<<<dim3(T_TOK / 32), dim3(256), 0, stream>>>(x, rw, sel, wts, cnt, xbuf);
  k_scan  <<<dim3(1), dim3(64), 0, stream>>>(cnt, offs);
  k_scatter<<<dim3(ROWS / 256), dim3(256), 0, stream>>>(sel, offs, cur, rtok, pos);
  k_gemm1 <<<dim3(MAXTILES, 4), dim3(256), 0, stream>>>(xbuf, W13p, rtok, offs, hbuf);
  k_gemm2 <<<dim3(MAXTILES, 8), dim3(256), 0, stream>>>(hbuf, W2t, offs, ybuf);
  k_combine<<<dim3(T_TOK / 4), dim3(256), 0, stream>>>(ybuf, pos, wts, out);
}

// Round 4
// 487.782 us; speedup vs baseline: 1.1869x; 1.1869x over previous
//
#include <hip/hip_runtime.h>
#include <cstdint>
#include <cstddef>
#include <math.h>

#define T_TOK 32768
#define DIM   1024
#define DFF   256
#define NE    8
#define NB    16                 // (expert, slot) bins
#define ROWS  (T_TOK * 2)        // 65536 token-expert rows
#define MAXROWS 66560            // ROWS + 16*63 pad, rounded to x64
#define MAXTILES (MAXROWS / 64)  // 1040

typedef unsigned short u16;
typedef __attribute__((ext_vector_type(8))) short v8s;   // 8 bf16 (4 VGPR)
typedef __attribute__((ext_vector_type(4))) float v4f;   // MFMA acc

__device__ __forceinline__ u16 f2bf(float f) {
  union { float f; unsigned u; } v; v.f = f;
  return (u16)((v.u + 0x7FFFu + ((v.u >> 16) & 1u)) >> 16);  // RNE
}
__device__ __forceinline__ float bf2f(u16 b) {
  union { unsigned u; float f; } v; v.u = ((unsigned)b) << 16; return v.f;
}

// async global->LDS, 16B per lane; LDS dest = wave-uniform base + lane*16
__device__ __forceinline__ void gload16(const u16* g, u16* l) {
  __builtin_amdgcn_global_load_lds(
      (const __attribute__((address_space(1))) void*)g,
      (__attribute__((address_space(3))) void*)l, 16, 0, 0);
}

// ---------------- ws layout (bytes) ----------------
#define WS_W13  ((size_t)0)              // 8*512*1024*2   = 8388608
#define WS_W2T  ((size_t)8388608)        // 8*1024*256*2   = 4194304
#define WS_H    ((size_t)12582912)       // 66560*256*2    = 34078720
#define WS_Y    ((size_t)46661632)       // 66560*1024*2   = 136314880
#define WS_RTOK ((size_t)182976512)      // 66560*4        = 266240
#define WS_POS  ((size_t)183242752)      // 65536*4        = 262144
#define WS_CNT  ((size_t)183504896)      // 16*4 pad 64
#define WS_CUR  ((size_t)183504960)      // 16*4 pad 64
#define WS_OFF  ((size_t)183505024)      // 17*4 pad 128
#define WS_SEL  ((size_t)183505152)      // 65536*4        = 262144
#define WS_WTS  ((size_t)183767296)      // 65536*4  -> total 184029440
// xb (bf16 x, 32768*1024*2 = 67108864 B) ALIASES the Y region: written by
// k_router, consumed by k_gemm1, dead before k_gemm2 overwrites Y.
#define WS_XB   WS_Y

// ============ weight packing: w1/w3 -> W13p[e][n=512][k=1024] bf16 ============
__global__ __launch_bounds__(256) void k_pack13(const float* __restrict__ w1,
                                                const float* __restrict__ w3,
                                                u16* __restrict__ W13p) {
  __shared__ float s1[32][33];
  __shared__ float s3[32][33];
  int e = blockIdx.z, k0 = blockIdx.x * 32, j0w = blockIdx.y;
  int tx = threadIdx.x, ty = threadIdx.y;
  size_t wbase = (size_t)e * DIM * DFF;
#pragma unroll
  for (int r = 0; r < 4; ++r) {
    int kl = ty + 8 * r;
    size_t src = wbase + (size_t)(k0 + kl) * DFF + j0w * 32 + tx;
    s1[kl][tx] = w1[src];
    s3[kl][tx] = w3[src];
  }
  __syncthreads();
  size_t obase = (size_t)e * 512 * 1024;
#pragma unroll
  for (int r = 0; r < 4; ++r) {
    int jl = ty + 8 * r;
    int n1 = 64 * j0w + jl;
    W13p[obase + (size_t)n1 * 1024 + k0 + tx]        = f2bf(s1[tx][jl]);
    W13p[obase + (size_t)(n1 + 32) * 1024 + k0 + tx] = f2bf(s3[tx][jl]);
  }
}

// ============ w2 [e][k=256][n=1024] -> W2t[e][n=1024][k=256] bf16 ============
__global__ __launch_bounds__(256) void k_pack2(const float* __restrict__ w2,
                                               u16* __restrict__ W2t) {
  __shared__ float s[32][33];
  int e = blockIdx.z, k0 = blockIdx.x * 32, n0 = blockIdx.y * 32;
  int tx = threadIdx.x, ty = threadIdx.y;
#pragma unroll
  for (int r = 0; r < 4; ++r) {
    int kl = ty + 8 * r;
    s[kl][tx] = w2[(size_t)e * DFF * DIM + (size_t)(k0 + kl) * DIM + n0 + tx];
  }
  __syncthreads();
#pragma unroll
  for (int r = 0; r < 4; ++r) {
    int nl = ty + 8 * r;
    W2t[(size_t)e * DIM * DFF + (size_t)(n0 + nl) * DFF + k0 + tx] = f2bf(s[tx][nl]);
  }
}

// ============ router: np-order fp32 logits, LDS-staged; also emits xb bf16 ====
__global__ __launch_bounds__(256) void k_router(const float* __restrict__ x,
                                                const float* __restrict__ rw,
                                                int* __restrict__ sel,
                                                float* __restrict__ wts,
                                                int* __restrict__ cnt,
                                                u16* __restrict__ xb) {
  __shared__ __align__(16) float s_rw[NE][1028];
  __shared__ __align__(16) float s_x[32][132];
  __shared__ float s_lg[256];
  __shared__ int s_cnt[NB];
  int tid = threadIdx.x;
  if (tid < NB) s_cnt[tid] = 0;
  {
    const float4* rw4 = (const float4*)rw;
#pragma unroll
    for (int r = 0; r < 8; ++r)
      *(float4*)(&s_rw[r][tid * 4]) = rw4[r * 256 + tid];
  }
  int tl = tid >> 3, e = tid & 7;
  float acc = 0.0f;
  const float4* x4 = (const float4*)x;
  for (int c = 0; c < 8; ++c) {          // 8 chunks of 128 k
    __syncthreads();
#pragma unroll
    for (int j = 0; j < 4; ++j) {
      int slot = j * 256 + tid;
      int t = slot >> 5, kk = (slot & 31) * 4;
      *(float4*)(&s_x[t][kk]) = x4[((size_t)blockIdx.x * 32 + t) * 256 + c * 32 + (slot & 31)];
    }
    __syncthreads();
    const float* xp = &s_x[tl][0];
    const float* wp = &s_rw[e][c * 128];
#pragma unroll 16
    for (int k = 0; k < 128; ++k) acc = fmaf(xp[k], wp[k], acc);  // strict sequential
    // emit bf16 x for this chunk (same RNE f2bf -> bit-identical GEMM1)
    {
      int t2 = tid >> 3, k2 = (tid & 7) * 16;
      const float* sp = &s_x[t2][k2];
      u16 tb[16];
#pragma unroll
      for (int k = 0; k < 16; ++k) tb[k] = f2bf(sp[k]);
      u16* xo = xb + ((size_t)(blockIdx.x * 32 + t2)) * 1024 + c * 128 + k2;
      *(uint4*)(xo)     = *(const uint4*)(&tb[0]);
      *(uint4*)(xo + 8) = *(const uint4*)(&tb[8]);
    }
  }
  s_lg[tid] = acc;
  __syncthreads();
  if ((tid & 7) == 0) {
    int t = blockIdx.x * 32 + tl;
    const float* lg = s_lg + tid;
    int b0 = 0; float v0 = lg[0];
#pragma unroll
    for (int ee = 1; ee < NE; ++ee) if (lg[ee] > v0) { v0 = lg[ee]; b0 = ee; }
    int b1 = -1; float v1 = -1e30f;
#pragma unroll
    for (int ee = 0; ee < NE; ++ee) if (ee != b0 && lg[ee] > v1) { v1 = lg[ee]; b1 = ee; }
    float w0 = 1.0f / (1.0f + expf(v1 - v0));  // v1<=v0, safe
    sel[2 * t] = b0; sel[2 * t + 1] = b1;
    wts[2 * t] = w0; wts[2 * t + 1] = 1.0f - w0;
    atomicAdd(&s_cnt[2 * b0], 1);       // bin = expert*2 + slot
    atomicAdd(&s_cnt[2 * b1 + 1], 1);
  }
  __syncthreads();
  if (tid < NB && s_cnt[tid]) atomicAdd(&cnt[tid], s_cnt[tid]);
}

// ============ scan: padded (x64) exclusive offsets over 16 bins ============
__global__ void k_scan(const int* __restrict__ cnt, int* __restrict__ offs) {
  if (threadIdx.x == 0 && blockIdx.x == 0) {
    int o = 0;
#pragma unroll
    for (int b = 0; b < NB; ++b) { offs[b] = o; o += (cnt[b] + 63) & ~63; }
    offs[NB] = o;
  }
}

// ============ scatter: build (expert,slot)-sorted row lists + pos map ============
__global__ __launch_bounds__(256) void k_scatter(const int* __restrict__ sel,
                                                 const int* __restrict__ offs,
                                                 int* __restrict__ cursor,
                                                 int* __restrict__ rtok,
                                                 int* __restrict__ pos) {
  __shared__ int s_cnt[NB], s_base[NB];
  int tid = threadIdx.x;
  if (tid < NB) s_cnt[tid] = 0;
  __syncthreads();
  int g = blockIdx.x * 256 + tid;          // token*2 + slot
  int b = sel[g] * 2 + (g & 1);
  int lpos = atomicAdd(&s_cnt[b], 1);
  __syncthreads();
  if (tid < NB) s_base[tid] = s_cnt[tid] ? atomicAdd(&cursor[tid], s_cnt[tid]) : 0;
  __syncthreads();
  int row = offs[b] + s_base[b] + lpos;
  rtok[row] = g >> 1;
  pos[g] = row;
}

// =============================================================================
// GEMM1 + SwiGLU (round-2 geometry: 64x512 tile, 8 waves, full N per block).
// Rotated pipeline: 2 tiles prefetched in prologue; per iter, wait vmcnt(5)
// (counted, never 0 mid-loop) for the tile staged a FULL iteration earlier;
// issue t+2 right after the frag-read barrier. sched_barrier(0) pins the
// stage-issue BEFORE the MFMA cluster (round-2's bug: scheduler sank it).
// All 8 waves issue exactly 5 gloads/step (waves 0-3 duplicate-stage A).
// =============================================================================
__global__ __launch_bounds__(512, 4) void k_gemm1(const u16* __restrict__ xb,
                                                  const u16* __restrict__ W13p,
                                                  const int* __restrict__ rtok,
                                                  const int* __restrict__ offs,
                                                  u16* __restrict__ h) {
  __shared__ __align__(16) u16 A_s[2][64][32];
  __shared__ __align__(16) u16 B_s[2][512][32];
  // chunked XCD swizzle (1040 % 8 == 0, bijective)
  int bx = (int)((blockIdx.x & 7) * (MAXTILES / 8) + (blockIdx.x >> 3));
  int row0 = bx * 64;
  if (row0 >= offs[NB]) return;
  int b2 = 0;
  while (row0 >= offs[b2 + 1]) ++b2;
  int e = b2 >> 1;
  int tid = threadIdx.x;
  int wv = tid >> 6, lane = tid & 63;
  int lr = lane & 15, q = lane >> 4;
  int qa = q ^ ((lr >> 1) & 3);            // swizzled read chunk
  int srow = lane >> 2;                    // staged row within 16-row group
  int schk = (lane & 3) ^ ((lane >> 3) & 3);  // pre-swizzled source chunk
  const u16* srcB = W13p + (size_t)e * 512 * 1024
                  + (size_t)(64 * wv + srow) * 1024 + schk * 8;
  int arow = 16 * (wv & 3) + srow;         // all waves stage A (dup across halves)
  int tk = rtok[row0 + arow]; if (tk < 0) tk = 0;   // pad row -> token 0
  const u16* srcA = xb + (size_t)tk * 1024 + schk * 8;
  v4f acc[4][4] = {};
  v8s a_[4], b_[4];

#define G1_STAGE(buf, k0) do {                                              \
    u16* ldsB_ = &B_s[buf][64 * wv][0];                                     \
    _Pragma("unroll")                                                       \
    for (int i_ = 0; i_ < 4; ++i_)                                          \
      gload16(srcB + (size_t)i_ * 16 * 1024 + (k0), ldsB_ + i_ * 512);      \
    gload16(srcA + (k0), &A_s[buf][(wv & 3) * 16][0]);                      \
  } while (0)

#define G1_LOAD(buf) do {                                                   \
    _Pragma("unroll")                                                       \
    for (int mt_ = 0; mt_ < 4; ++mt_)                                       \
      a_[mt_] = *(const v8s*)(&A_s[buf][16 * mt_ + lr][qa * 8]);            \
    _Pragma("unroll")                                                       \
    for (int nt_ = 0; nt_ < 4; ++nt_)                                       \
      b_[nt_] = *(const v8s*)(&B_s[buf][64 * wv + 16 * nt_ + lr][qa * 8]);  \
  } while (0)

#define G1_MFMA() do {                                                      \
    _Pragma("unroll")                                                       \
    for (int mt_ = 0; mt_ < 4; ++mt_)                                       \
      _Pragma("unroll")                                                     \
      for (int nt_ = 0; nt_ < 4; ++nt_)                                     \
        acc[mt_][nt_] = __builtin_amdgcn_mfma_f32_16x16x32_bf16(            \
            a_[mt_], b_[nt_], acc[mt_][nt_], 0, 0, 0);                      \
  } while (0)

  G1_STAGE(0, 0);
  G1_STAGE(1, 32);
  asm volatile("s_waitcnt vmcnt(5)" ::: "memory");   // tile 0 landed
  __builtin_amdgcn_s_barrier();
  __builtin_amdgcn_sched_barrier(0);
#pragma unroll 2
  for (int t = 0; t < 30; ++t) {
    int cur = t & 1;
    G1_LOAD(cur);
    asm volatile("s_waitcnt lgkmcnt(0)" ::: "memory");
    __builtin_amdgcn_sched_barrier(0);
    __builtin_amdgcn_s_barrier();            // all frags read -> buf reusable
    __builtin_amdgcn_sched_barrier(0);
    G1_STAGE(cur, (t + 2) * 32);             // issue t+2 early (overlaps MFMA)
    __builtin_amdgcn_sched_barrier(0);
    __builtin_amdgcn_s_setprio(1);
    G1_MFMA();
    __builtin_amdgcn_s_setprio(0);
    asm volatile("s_waitcnt vmcnt(5)" ::: "memory");  // tile t+1 landed
    __builtin_amdgcn_s_barrier();
    __builtin_amdgcn_sched_barrier(0);
  }
  // t = 30 (buf 0): no more stages into buf 0
  G1_LOAD(0);
  asm volatile("s_waitcnt lgkmcnt(0)" ::: "memory");
  __builtin_amdgcn_sched_barrier(0);
  G1_MFMA();
  asm volatile("s_waitcnt vmcnt(0)" ::: "memory");    // tile 31 landed
  __builtin_amdgcn_s_barrier();
  __builtin_amdgcn_sched_barrier(0);
  // t = 31 (buf 1)
  G1_LOAD(1);
  asm volatile("s_waitcnt lgkmcnt(0)" ::: "memory");
  __builtin_amdgcn_sched_barrier(0);
  G1_MFMA();

#pragma unroll
  for (int mt = 0; mt < 4; ++mt)
#pragma unroll
    for (int nt = 0; nt < 2; ++nt)
#pragma unroll
      for (int r = 0; r < 4; ++r) {
        float x1 = bf2f(f2bf(acc[mt][nt][r]));      // match ref bf16 rounding
        float x3 = bf2f(f2bf(acc[mt][nt + 2][r]));
        float hv = x1 * x3 / (1.0f + __expf(-x1));  // silu(x1)*x3
        int row = row0 + 16 * mt + q * 4 + r;
        int col = 32 * wv + 16 * nt + lr;
        h[(size_t)row * DFF + col] = f2bf(hv);
      }
#undef G1_STAGE
#undef G1_LOAD
#undef G1_MFMA
}

// ============ GEMM2: y[row][1024] bf16, same rotated pipeline (8 K-steps) =====
__global__ __launch_bounds__(512, 4) void k_gemm2(const u16* __restrict__ h,
                                                  const u16* __restrict__ W2t,
                                                  const int* __restrict__ offs,
                                                  u16* __restrict__ y) {
  __shared__ __align__(16) u16 A_s[2][64][32];
  __shared__ __align__(16) u16 B_s[2][512][32];  // buf0 reused as T[16][520] in epilogue
  int bx = (int)((blockIdx.x & 7) * (MAXTILES / 8) + (blockIdx.x >> 3));
  int row0 = bx * 64;
  if (row0 >= offs[NB]) return;
  int b2 = 0;
  while (row0 >= offs[b2 + 1]) ++b2;
  int e = b2 >> 1;
  int nb = blockIdx.y;
  int tid = threadIdx.x;
  int wv = tid >> 6, lane = tid & 63;
  int lr = lane & 15, q = lane >> 4;
  int qa = q ^ ((lr >> 1) & 3);
  int srow = lane >> 2;
  int schk = (lane & 3) ^ ((lane >> 3) & 3);
  const u16* srcB = W2t + (size_t)e * DIM * DFF + (size_t)nb * 512 * DFF
                  + (size_t)(64 * wv + srow) * DFF + schk * 8;
  int arow = 16 * (wv & 3) + srow;
  const u16* srcA = h + (size_t)(row0 + arow) * DFF + schk * 8;
  v4f acc[4][4] = {};
  v8s a_[4], b_[4];

#define G2_STAGE(buf, k0) do {                                              \
    u16* ldsB_ = &B_s[buf][64 * wv][0];                                     \
    _Pragma("unroll")                                                       \
    for (int i_ = 0; i_ < 4; ++i_)                                          \
      gload16(srcB + (size_t)i_ * 16 * DFF + (k0), ldsB_ + i_ * 512);       \
    gload16(srcA + (k0), &A_s[buf][(wv & 3) * 16][0]);                      \
  } while (0)

#define G2_LOAD(buf) do {                                                   \
    _Pragma("unroll")                                                       \
    for (int mt_ = 0; mt_ < 4; ++mt_)                                       \
      a_[mt_] = *(const v8s*)(&A_s[buf][16 * mt_ + lr][qa * 8]);            \
    _Pragma("unroll")                                                       \
    for (int nt_ = 0; nt_ < 4; ++nt_)                                       \
      b_[nt_] = *(const v8s*)(&B_s[buf][64 * wv + 16 * nt_ + lr][qa * 8]);  \
  } while (0)

#define G2_MFMA() do {                                                      \
    _Pragma("unroll")                                                       \
    for (int mt_ = 0; mt_ < 4; ++mt_)                                       \
      _Pragma("unroll")                                                     \
      for (int nt_ = 0; nt_ < 4; ++nt_)                                     \
        acc[mt_][nt_] = __builtin_amdgcn_mfma_f32_16x16x32_bf16(            \
            a_[mt_], b_[nt_], acc[mt_][nt_], 0, 0, 0);                      \
  } while (0)

  G2_STAGE(0, 0);
  G2_STAGE(1, 32);
  asm volatile("s_waitcnt vmcnt(5)" ::: "memory");
  __builtin_amdgcn_s_barrier();
  __builtin_amdgcn_sched_barrier(0);
#pragma unroll 2
  for (int t = 0; t < 6; ++t) {
    int cur = t & 1;
    G2_LOAD(cur);
    asm volatile("s_waitcnt lgkmcnt(0)" ::: "memory");
    __builtin_amdgcn_sched_barrier(0);
    __builtin_amdgcn_s_barrier();
    __builtin_amdgcn_sched_barrier(0);
    G2_STAGE(cur, (t + 2) * 32);
    __builtin_amdgcn_sched_barrier(0);
    __builtin_amdgcn_s_setprio(1);
    G2_MFMA();
    __builtin_amdgcn_s_setprio(0);
    asm volatile("s_waitcnt vmcnt(5)" ::: "memory");
    __builtin_amdgcn_s_barrier();
    __builtin_amdgcn_sched_barrier(0);
  }
  // t = 6 (buf 0)
  G2_LOAD(0);
  asm volatile("s_waitcnt lgkmcnt(0)" ::: "memory");
  __builtin_amdgcn_sched_barrier(0);
  G2_MFMA();
  asm volatile("s_waitcnt vmcnt(0)" ::: "memory");
  __builtin_amdgcn_s_barrier();
  __builtin_amdgcn_sched_barrier(0);
  // t = 7 (buf 1)
  G2_LOAD(1);
  asm volatile("s_waitcnt lgkmcnt(0)" ::: "memory");
  __builtin_amdgcn_sched_barrier(0);
  G2_MFMA();
  __syncthreads();                       // all waves done reading B_s before Ts reuse

  // epilogue: per 16-row slab (mt), LDS transpose -> coalesced uint4 stores
  u16* Ts = &B_s[0][0][0];                   // viewed as [16][520] (fits in buf 0)
#pragma unroll
  for (int mt = 0; mt < 4; ++mt) {
#pragma unroll
    for (int nt = 0; nt < 4; ++nt)
#pragma unroll
      for (int r = 0; r < 4; ++r)
        Ts[(q * 4 + r) * 520 + 64 * wv + 16 * nt + lr] = f2bf(acc[mt][nt][r]);
    __syncthreads();
#pragma unroll
    for (int i = 0; i < 2; ++i) {
      int j = tid + 512 * i;                 // 1024 uint4 slots = 16 rows x 64
      int rr = j >> 6, cc = j & 63;
      uint4 v = *(const uint4*)(Ts + rr * 520 + cc * 8);
      *(uint4*)(y + (size_t)(row0 + 16 * mt + rr) * 1024 + nb * 512 + cc * 8) = v;
    }
    __syncthreads();
  }
#undef G2_STAGE
#undef G2_LOAD
#undef G2_MFMA
}

// ============ combine: out[t] = w0*fp32(y[pos0]) + w1*fp32(y[pos1]) ============
__global__ __launch_bounds__(256) void k_combine(const u16* __restrict__ y,
                                                 const int* __restrict__ pos,
                                                 const float* __restrict__ wts,
                                                 float* __restrict__ out) {
  int tid = threadIdx.x, wv = tid >> 6, lane = tid & 63;
  int t = blockIdx.x * 4 + wv;
  int r0 = pos[2 * t], r1 = pos[2 * t + 1];
  float w0 = wts[2 * t], w1 = wts[2 * t + 1];
  const uint4* y0 = (const uint4*)(y + (size_t)r0 * 1024);
  const uint4* y1 = (const uint4*)(y + (size_t)r1 * 1024);
  float* o = out + (size_t)t * 1024;
#pragma unroll
  for (int i = 0; i < 2; ++i) {
    int j = lane + 64 * i;                   // 128 uint4 per row
    uint4 a = y0[j], b = y1[j];
    const u16* pa = (const u16*)&a;
    const u16* pb = (const u16*)&b;
    float f[8];
#pragma unroll
    for (int k = 0; k < 8; ++k) f[k] = bf2f(pa[k]) * w0 + bf2f(pb[k]) * w1;
    *(float4*)(o + j * 8)     = *(float4*)&f[0];
    *(float4*)(o + j * 8 + 4) = *(float4*)&f[4];
  }
}

extern "C" void kernel_launch(void* const* d_in, const int* in_sizes, int n_in,
                              void* d_out, int out_size, void* d_ws, size_t ws_size,
                              hipStream_t stream) {
  (void)in_sizes; (void)n_in; (void)ws_size; (void)out_size;
  const float* x  = (const float*)d_in[0];
  const float* rw = (const float*)d_in[1];
  const float* w1 = (const float*)d_in[2];
  const float* w2 = (const float*)d_in[3];
  const float* w3 = (const float*)d_in[4];
  float* out = (float*)d_out;
  char* ws = (char*)d_ws;
  u16*   W13p = (u16*)(ws + WS_W13);
  u16*   W2t  = (u16*)(ws + WS_W2T);
  u16*   hbuf = (u16*)(ws + WS_H);
  u16*   ybuf = (u16*)(ws + WS_Y);
  u16*   xbuf = (u16*)(ws + WS_XB);   // aliases ybuf: dead before k_gemm2 writes
  int*   rtok = (int*)(ws + WS_RTOK);
  int*   pos  = (int*)(ws + WS_POS);
  int*   cnt  = (int*)(ws + WS_CNT);
  int*   cur  = (int*)(ws + WS_CUR);
  int*   offs = (int*)(ws + WS_OFF);
  int*   sel  = (int*)(ws + WS_SEL);
  float* wts  = (float*)(ws + WS_WTS);

  hipMemsetAsync(ws + WS_RTOK, 0xFF, (size_t)MAXROWS * 4, stream);  // rtok = -1 (pad marker)
  hipMemsetAsync(ws + WS_CNT, 0, 128, stream);                      // cnt, cur

  k_pack13<<<dim3(32, 8, 8), dim3(32, 8), 0, stream>>>(w1, w3, W13p);
  k_pack2 <<<dim3(8, 32, 8), dim3(32, 8), 0, stream>>>(w2, W2t);
  k_router<<<dim3(T_TOK / 32), dim3(256), 0, stream>>>(x, rw, sel, wts, cnt, xbuf);
  k_scan  <<<dim3(1), dim3(64), 0, stream>>>(cnt, offs);
  k_scatter<<<dim3(ROWS / 256), dim3(256), 0, stream>>>(sel, offs, cur, rtok, pos);
  k_gemm1 <<<dim3(MAXTILES), dim3(512), 0, stream>>>(xbuf, W13p, rtok, offs, hbuf);
  k_gemm2 <<<dim3(MAXTILES, 2), dim3(512), 0, stream>>>(hbuf, W2t, offs, ybuf);
  k_combine<<<dim3(T_TOK / 4), dim3(256), 0, stream>>>(ybuf, pos, wts, out);
}